// Round 1
// baseline (79.465 us; speedup 1.0000x reference)
//
#include <hip/hip_runtime.h>

// Problem constants (from reference setup_inputs):
//   x:       [64, 1, 257, 257] f32
//   conv_w:  [1, 1, 2, 2]      f32
//   conv_b:  [1]               f32
//   qparams: [2, 4]            f32  -- provably irrelevant (diag phases +
//            CNOT permutations cannot change Z-basis probabilities)
// Output: [64, 2, 256, 256] f32 = concat(cls, qmap) on channel axis.
// qmap closed form: cos(cls_TL) * cos(cls_TR) * cos(cls_BR) per 2x2 block.

#define BATCH 64
#define INH   257
#define INW   257
#define OH    256
#define OW    256
#define HP    128   // OH / 2
#define WP    128   // OW / 2

__global__ __launch_bounds__(256) void conv_enh_fused(
    const float* __restrict__ x,
    const float* __restrict__ cw,
    const float* __restrict__ cb,
    float* __restrict__ out)
{
    const int tid = blockIdx.x * blockDim.x + threadIdx.x;
    // tid in [0, BATCH*HP*WP); j fastest for coalescing
    const int j    = tid & (WP - 1);
    const int rest = tid >> 7;
    const int i    = rest & (HP - 1);
    const int b    = rest >> 7;

    const float w00 = cw[0], w01 = cw[1], w10 = cw[2], w11 = cw[3];
    const float bias = cb[0];

    const int r0 = 2 * i;
    const int c0 = 2 * j;
    const float* __restrict__ row0 = x + (size_t)b * INH * INW + (size_t)r0 * INW + c0;
    const float* __restrict__ row1 = row0 + INW;
    const float* __restrict__ row2 = row1 + INW;

    const float x00 = row0[0], x01 = row0[1], x02 = row0[2];
    const float x10 = row1[0], x11 = row1[1], x12 = row1[2];
    const float x20 = row2[0], x21 = row2[1], x22 = row2[2];

    // cross-correlation (JAX conv_general_dilated semantics) + bias + ReLU
    const float c00 = fmaxf(fmaf(w11, x11, fmaf(w10, x10, fmaf(w01, x01, fmaf(w00, x00, bias)))), 0.f);
    const float c01 = fmaxf(fmaf(w11, x12, fmaf(w10, x11, fmaf(w01, x02, fmaf(w00, x01, bias)))), 0.f);
    const float c10 = fmaxf(fmaf(w11, x21, fmaf(w10, x20, fmaf(w01, x11, fmaf(w00, x10, bias)))), 0.f);
    const float c11 = fmaxf(fmaf(w11, x22, fmaf(w10, x21, fmaf(w01, x12, fmaf(w00, x11, bias)))), 0.f);

    // expval of PauliZ(0) after RX layer + (RZ diag + CNOT ring) x2:
    // collapses to cos(TL)*cos(TR)*cos(BR); qparams cancel exactly.
    const float q = __cosf(c00) * __cosf(c01) * __cosf(c11);

    float* __restrict__ o0 = out + (size_t)b * 2 * OH * OW + (size_t)r0 * OW + c0;
    float* __restrict__ o1 = o0 + OH * OW;

    *(float2*)o0        = make_float2(c00, c01);
    *(float2*)(o0 + OW) = make_float2(c10, c11);
    const float2 qq = make_float2(q, q);
    *(float2*)o1        = qq;
    *(float2*)(o1 + OW) = qq;
}

extern "C" void kernel_launch(void* const* d_in, const int* in_sizes, int n_in,
                              void* d_out, int out_size, void* d_ws, size_t ws_size,
                              hipStream_t stream)
{
    const float* x  = (const float*)d_in[0];
    const float* cw = (const float*)d_in[1];
    const float* cb = (const float*)d_in[2];
    // d_in[3] (qparams) provably does not affect the output.
    float* out = (float*)d_out;

    const int total  = BATCH * HP * WP;   // 1,048,576 threads
    const int block  = 256;
    const int grid   = total / block;     // 4096 blocks
    conv_enh_fused<<<grid, block, 0, stream>>>(x, cw, cb, out);
}

// Round 2
// 78.933 us; speedup vs baseline: 1.0067x; 1.0067x over previous
//
#include <hip/hip_runtime.h>

// Problem: x [64,1,257,257] f32, conv_w [1,1,2,2], conv_b [1], qparams [2,4].
// Output [64,2,256,256] f32 = concat(conv-relu, qmap) on channel axis.
//
// Analytic collapse (verified R1, absmax 0.0625):
//   - qparams are provably irrelevant: the circuit after the RX product layer
//     is P·D2·P·D1 (D diagonal phases, P basis permutations) — neither changes
//     Z-basis probabilities.
//   - expval = cos(TL)*cos(TR)*cos(BR) of each 2x2 post-ReLU conv block
//     (sign of bit0 of F^2(k) = b0^b1^b3 factorizes over the product state).
//
// R2: one thread per TWO horizontal patches (4 cols x 2 rows of output).
//   15 scalar loads + 4 aligned float4 stores per 16 outputs
//   (was 18 loads + 8 float2 stores per 16 outputs across 2 threads).

#define BATCH 64
#define INH   257
#define INW   257
#define OH    256
#define OW    256
#define HP    128          // patch rows
#define WG2   64           // col-groups of 2 patches (4 output cols)

__global__ __launch_bounds__(256) void conv_enh_fused2(
    const float* __restrict__ x,
    const float* __restrict__ cw,
    const float* __restrict__ cb,
    float* __restrict__ out)
{
    const int tid = blockIdx.x * blockDim.x + threadIdx.x;
    // tid in [0, 64*128*64); col-group fastest for coalescing
    const int j  = tid & (WG2 - 1);          // 0..63  -> output cols 4j..4j+3
    const int i  = (tid >> 6) & (HP - 1);    // 0..127 -> output rows 2i, 2i+1
    const int b  = tid >> 13;                // 0..63

    const float w00 = cw[0], w01 = cw[1], w10 = cw[2], w11 = cw[3];
    const float bias = cb[0];

    const int r0 = 2 * i;
    const int c0 = 4 * j;
    const float* __restrict__ p0 = x + (size_t)b * INH * INW + (size_t)r0 * INW + c0;
    const float* __restrict__ p1 = p0 + INW;
    const float* __restrict__ p2 = p1 + INW;

    float a0 = p0[0], a1 = p0[1], a2 = p0[2], a3 = p0[3], a4 = p0[4];
    float m0 = p1[0], m1 = p1[1], m2 = p1[2], m3 = p1[3], m4 = p1[4];
    float z0 = p2[0], z1 = p2[1], z2 = p2[2], z3 = p2[3], z4 = p2[4];

    // cross-correlation + bias + ReLU; top row (r0) and bottom row (r0+1)
    const float t0 = fmaxf(fmaf(w11, m1, fmaf(w10, m0, fmaf(w01, a1, fmaf(w00, a0, bias)))), 0.f);
    const float t1 = fmaxf(fmaf(w11, m2, fmaf(w10, m1, fmaf(w01, a2, fmaf(w00, a1, bias)))), 0.f);
    const float t2 = fmaxf(fmaf(w11, m3, fmaf(w10, m2, fmaf(w01, a3, fmaf(w00, a2, bias)))), 0.f);
    const float t3 = fmaxf(fmaf(w11, m4, fmaf(w10, m3, fmaf(w01, a4, fmaf(w00, a3, bias)))), 0.f);
    const float u0 = fmaxf(fmaf(w11, z1, fmaf(w10, z0, fmaf(w01, m1, fmaf(w00, m0, bias)))), 0.f);
    const float u1 = fmaxf(fmaf(w11, z2, fmaf(w10, z1, fmaf(w01, m2, fmaf(w00, m1, bias)))), 0.f);
    const float u2 = fmaxf(fmaf(w11, z3, fmaf(w10, z2, fmaf(w01, m3, fmaf(w00, m2, bias)))), 0.f);
    const float u3 = fmaxf(fmaf(w11, z4, fmaf(w10, z3, fmaf(w01, m4, fmaf(w00, m3, bias)))), 0.f);

    // qmap per 2x2 patch: cos(TL)*cos(TR)*cos(BR)
    const float q0 = __cosf(t0) * __cosf(t1) * __cosf(u1);
    const float q1 = __cosf(t2) * __cosf(t3) * __cosf(u3);

    float* __restrict__ o0 = out + (size_t)b * 2 * OH * OW + (size_t)r0 * OW + c0;
    float* __restrict__ o1 = o0 + OH * OW;

    *(float4*)o0        = make_float4(t0, t1, t2, t3);
    *(float4*)(o0 + OW) = make_float4(u0, u1, u2, u3);
    const float4 qq = make_float4(q0, q0, q1, q1);
    *(float4*)o1        = qq;
    *(float4*)(o1 + OW) = qq;
}

extern "C" void kernel_launch(void* const* d_in, const int* in_sizes, int n_in,
                              void* d_out, int out_size, void* d_ws, size_t ws_size,
                              hipStream_t stream)
{
    const float* x  = (const float*)d_in[0];
    const float* cw = (const float*)d_in[1];
    const float* cb = (const float*)d_in[2];
    // d_in[3] (qparams) provably does not affect the output.
    float* out = (float*)d_out;

    const int total = BATCH * HP * WG2;   // 524,288 threads
    const int block = 256;
    const int grid  = total / block;      // 2048 blocks
    conv_enh_fused2<<<grid, block, 0, stream>>>(x, cw, cb, out);
}